// Round 1
// baseline (551.380 us; speedup 1.0000x reference)
//
#include <hip/hip_runtime.h>
#include <hip/hip_bf16.h>
#include <math.h>

// Problem dims
#define NPOS   1024      // spatial positions (h*w) = "batch" of the mamba block
#define NSAMP  16        // samples = scan length L
#define DMODEL 256
#define DINNER 512
#define DSTATE 16
#define DTRANK 16
#define MROWS  (NPOS*NSAMP)   // 16384, m = s*1024 + p

// ---------------- K0: RMS scale per row ----------------
__global__ __launch_bounds__(256) void k0_scale(const float* __restrict__ feat,
                                                float* __restrict__ scale) {
    int m = blockIdx.x * 256 + threadIdx.x;   // 16384 threads
    int s = m >> 10, p = m & 1023;
    const float* base = feat + (size_t)s * (DMODEL * NPOS) + p;
    float ss = 0.f;
    #pragma unroll 4
    for (int c = 0; c < DMODEL; ++c) {
        float v = base[(size_t)c * NPOS];
        ss += v * v;
    }
    scale[m] = rsqrtf(ss * (1.f / DMODEL) + 1e-5f);
}

// ---------------- K1: xr = rmsnorm(x) @ w_in  (M=16384,K=256,N=1024) ----------------
#define BM 64
#define BN 64
#define BK 16
__global__ __launch_bounds__(256) void k1_gemm(const float* __restrict__ feat,
                                               const float* __restrict__ scale,
                                               const float* __restrict__ norm_w,
                                               const float* __restrict__ w_in,
                                               float* __restrict__ xr) {
    __shared__ float As[BK][BM + 1];
    __shared__ float Bs[BK][BN];
    int t = threadIdx.x;
    int tx = t & 15, ty = t >> 4;
    int m0 = blockIdx.y * BM, n0 = blockIdx.x * BN;
    int s = m0 >> 10, p0 = m0 & 1023;
    int a_mi = t & 63, a_k0 = t >> 6;     // A: 64 m x 16 k
    int b_nj = t & 63, b_k0 = t >> 6;     // B: 16 k x 64 n
    float sc = scale[m0 + a_mi];
    float acc[4][4] = {};
    for (int k0 = 0; k0 < DMODEL; k0 += BK) {
        #pragma unroll
        for (int q = 0; q < 4; ++q) {
            int kj = a_k0 + 4 * q;
            float v = feat[(size_t)s * (DMODEL * NPOS) + (size_t)(k0 + kj) * NPOS + p0 + a_mi];
            As[kj][a_mi] = v * sc * norm_w[k0 + kj];
        }
        #pragma unroll
        for (int q = 0; q < 4; ++q) {
            int kj = b_k0 + 4 * q;
            Bs[kj][b_nj] = w_in[(size_t)(k0 + kj) * 1024 + n0 + b_nj];
        }
        __syncthreads();
        #pragma unroll
        for (int k = 0; k < BK; ++k) {
            float a[4], b[4];
            #pragma unroll
            for (int i = 0; i < 4; ++i) a[i] = As[k][ty + 16 * i];
            #pragma unroll
            for (int j = 0; j < 4; ++j) b[j] = Bs[k][tx + 16 * j];
            #pragma unroll
            for (int i = 0; i < 4; ++i)
                #pragma unroll
                for (int j = 0; j < 4; ++j) acc[i][j] += a[i] * b[j];
        }
        __syncthreads();
    }
    #pragma unroll
    for (int i = 0; i < 4; ++i) {
        int m = m0 + ty + 16 * i;
        #pragma unroll
        for (int j = 0; j < 4; ++j)
            xr[(size_t)m * 1024 + n0 + tx + 16 * j] = acc[i][j];
    }
}

// ---------------- K2: depthwise causal conv (k=3) over s + SiLU ----------------
__global__ __launch_bounds__(256) void k2_conv(const float* __restrict__ xr,
                                               const float* __restrict__ conv_w,
                                               const float* __restrict__ conv_b,
                                               float* __restrict__ xm) {
    int flat = blockIdx.x * 256 + threadIdx.x;  // (m,d), d fastest
    int d = flat & (DINNER - 1);
    int m = flat >> 9;
    int s = m >> 10;
    float w0 = conv_w[d * 3 + 0], w1 = conv_w[d * 3 + 1], w2 = conv_w[d * 3 + 2];
    float acc = conv_b[d];
    acc += xr[(size_t)m * 1024 + d] * w2;                               // t
    if (s >= 1) acc += xr[(size_t)(m - 1024) * 1024 + d] * w1;          // t-1
    if (s >= 2) acc += xr[(size_t)(m - 2048) * 1024 + d] * w0;          // t-2
    float sig = 1.f / (1.f + expf(-acc));
    xm[(size_t)m * DINNER + d] = acc * sig;
}

// ---------------- K3: dbc = xm @ w_xproj  (N=48) ----------------
__global__ __launch_bounds__(256) void k3_dbc(const float* __restrict__ xm,
                                              const float* __restrict__ w_xproj,
                                              float* __restrict__ dbc) {
    int flat = blockIdx.x * 256 + threadIdx.x;  // 16384*48 threads
    int j = flat % 48;
    int m = flat / 48;
    const float* xrow = xm + (size_t)m * DINNER;
    float acc = 0.f;
    #pragma unroll 8
    for (int k = 0; k < DINNER; ++k)
        acc += xrow[k] * w_xproj[k * 48 + j];
    dbc[(size_t)m * 48 + j] = acc;
}

// ---------------- K5: fused delta + selective scan + gates (y in-place over xm) ---
__global__ __launch_bounds__(256) void k5_scan(const float* __restrict__ xr,
                                               float* xm,  // in: xm, out: y (aliased)
                                               const float* __restrict__ dbc,
                                               const float* __restrict__ w_dt,
                                               const float* __restrict__ b_dt,
                                               const float* __restrict__ A_log,
                                               const float* __restrict__ Dp) {
    __shared__ float wdt[DTRANK][256];
    __shared__ float sdbc[48];
    int p = blockIdx.x >> 1;
    int d0 = (blockIdx.x & 1) << 8;
    int tx = threadIdx.x;
    int d = d0 + tx;
    #pragma unroll
    for (int r = 0; r < DTRANK; ++r) wdt[r][tx] = w_dt[r * DINNER + d];
    float Ar[DSTATE];
    #pragma unroll
    for (int n = 0; n < DSTATE; ++n) Ar[n] = -expf(A_log[d * DSTATE + n]);
    float Dv = Dp[d], bdt = b_dt[d];
    float h[DSTATE];
    #pragma unroll
    for (int n = 0; n < DSTATE; ++n) h[n] = 0.f;
    for (int s = 0; s < NSAMP; ++s) {
        int m = (s << 10) + p;
        __syncthreads();
        if (tx < 48) sdbc[tx] = dbc[(size_t)m * 48 + tx];
        __syncthreads();
        float dp = bdt;
        #pragma unroll
        for (int r = 0; r < DTRANK; ++r) dp += sdbc[r] * wdt[r][tx];
        float delta = (dp > 20.f) ? dp : log1pf(expf(dp));
        float u = xm[(size_t)m * DINNER + d];
        float yv = 0.f;
        #pragma unroll
        for (int n = 0; n < DSTATE; ++n) {
            float dA = expf(delta * Ar[n]);
            h[n] = dA * h[n] + delta * sdbc[16 + n] * u;
            yv += h[n] * sdbc[32 + n];
        }
        float r0 = xr[(size_t)m * 1024 + DINNER + d];   // res
        float sig = 1.f / (1.f + expf(-r0));
        xm[(size_t)m * DINNER + d] = (yv + u * Dv) * (r0 * sig);
    }
}

// ---------------- K6: out = y @ w_out + x  (N=256), writes (s,c,p) layout --------
__global__ __launch_bounds__(256) void k6_gemm(const float* __restrict__ y,
                                               const float* __restrict__ w_out,
                                               const float* __restrict__ feat,
                                               float* __restrict__ out) {
    __shared__ float As[BK][BM + 1];
    __shared__ float Bs[BK][BN];
    int t = threadIdx.x;
    int tx = t & 15, ty = t >> 4;
    int m0 = blockIdx.y * BM, n0 = blockIdx.x * BN;
    int s = m0 >> 10, p0 = m0 & 1023;
    int a_kj = t & 15, a_mi = t >> 4;   // A: 64 m x 16 k, k fastest across lanes
    int b_nj = t & 63, b_k0 = t >> 6;
    float acc[4][4] = {};
    for (int k0 = 0; k0 < DINNER; k0 += BK) {
        #pragma unroll
        for (int q = 0; q < 4; ++q) {
            int mi = a_mi + 16 * q;
            As[a_kj][mi] = y[(size_t)(m0 + mi) * DINNER + k0 + a_kj];
        }
        #pragma unroll
        for (int q = 0; q < 4; ++q) {
            int kj = b_k0 + 4 * q;
            Bs[kj][b_nj] = w_out[(size_t)(k0 + kj) * DMODEL + n0 + b_nj];
        }
        __syncthreads();
        #pragma unroll
        for (int k = 0; k < BK; ++k) {
            float a[4], b[4];
            #pragma unroll
            for (int i = 0; i < 4; ++i) a[i] = As[k][ty + 16 * i];
            #pragma unroll
            for (int j = 0; j < 4; ++j) b[j] = Bs[k][tx + 16 * j];
            #pragma unroll
            for (int i = 0; i < 4; ++i)
                #pragma unroll
                for (int j = 0; j < 4; ++j) acc[i][j] += a[i] * b[j];
        }
        __syncthreads();
    }
    #pragma unroll
    for (int i = 0; i < 4; ++i) {
        int pp = p0 + ty + 16 * i;
        #pragma unroll
        for (int j = 0; j < 4; ++j) {
            int c = n0 + tx + 16 * j;
            size_t idx = (size_t)s * (DMODEL * NPOS) + (size_t)c * NPOS + pp;
            out[idx] = acc[i][j] + feat[idx];
        }
    }
}

extern "C" void kernel_launch(void* const* d_in, const int* in_sizes, int n_in,
                              void* d_out, int out_size, void* d_ws, size_t ws_size,
                              hipStream_t stream) {
    const float* feature = (const float*)d_in[0];
    const float* norm_w  = (const float*)d_in[1];
    const float* w_in    = (const float*)d_in[2];
    const float* conv_w  = (const float*)d_in[3];
    const float* conv_b  = (const float*)d_in[4];
    const float* w_xproj = (const float*)d_in[5];
    const float* w_dt    = (const float*)d_in[6];
    const float* b_dt    = (const float*)d_in[7];
    const float* A_log   = (const float*)d_in[8];
    const float* Dp      = (const float*)d_in[9];
    const float* w_out   = (const float*)d_in[10];
    float* out = (float*)d_out;

    // workspace layout (fp32):
    char* ws = (char*)d_ws;
    float* scale = (float*)ws;                                   // 16384           (64 KB)
    float* xr    = (float*)(ws + 65536);                         // 16384 x 1024    (64 MB)
    float* xm    = (float*)(ws + 65536 + (size_t)MROWS*1024*4);  // 16384 x 512     (32 MB), reused as y
    float* dbc   = (float*)(ws + 65536 + (size_t)MROWS*1024*4 + (size_t)MROWS*512*4); // 16384 x 48 (3 MB)

    k0_scale<<<MROWS / 256, 256, 0, stream>>>(feature, scale);
    k1_gemm<<<dim3(1024 / BN, MROWS / BM), 256, 0, stream>>>(feature, scale, norm_w, w_in, xr);
    k2_conv<<<(MROWS * DINNER) / 256, 256, 0, stream>>>(xr, conv_w, conv_b, xm);
    k3_dbc<<<(MROWS * 48) / 256, 256, 0, stream>>>(xm, w_xproj, dbc);
    k5_scan<<<NPOS * 2, 256, 0, stream>>>(xr, xm, dbc, w_dt, b_dt, A_log, Dp);
    k6_gemm<<<dim3(DMODEL / BN, MROWS / BM), 256, 0, stream>>>(xm, w_out, feature, out);
}

// Round 2
// 399.326 us; speedup vs baseline: 1.3808x; 1.3808x over previous
//
#include <hip/hip_runtime.h>
#include <hip/hip_bf16.h>
#include <math.h>

// Problem dims
#define NPOS   1024
#define NSAMP  16
#define DMODEL 256
#define DINNER 512
#define DSTATE 16
#define DTRANK 16
#define MROWS  (NPOS*NSAMP)   // 16384, m = s*1024 + p

typedef __attribute__((ext_vector_type(8))) short short8;
typedef __attribute__((ext_vector_type(4))) float f32x4;

// fp32 -> bf16 round-to-nearest-even (finite inputs)
__device__ __forceinline__ unsigned short f2bf(float f) {
    unsigned int u = __builtin_bit_cast(unsigned int, f);
    u = u + 0x7FFFu + ((u >> 16) & 1u);
    return (unsigned short)(u >> 16);
}

// ---------------- K0: RMS scale per row ----------------
__global__ __launch_bounds__(256) void k0_scale(const float* __restrict__ feat,
                                                float* __restrict__ scale) {
    int m = blockIdx.x * 256 + threadIdx.x;
    int s = m >> 10, p = m & 1023;
    const float* base = feat + (size_t)s * (DMODEL * NPOS) + p;
    float ss = 0.f;
    #pragma unroll 4
    for (int c = 0; c < DMODEL; ++c) {
        float v = base[(size_t)c * NPOS];
        ss += v * v;
    }
    scale[m] = rsqrtf(ss * (1.f / DMODEL) + 1e-5f);
}

// ---------------- K1: xr = rmsnorm(x) @ w_in  (M=16384,K=256,N=1024), bf16 MFMA ---
// Tile 128x128, 4 waves (2x2 of 64x64), BK=32, LDS row stride 80B (conflict-free).
__global__ __launch_bounds__(256) void k1_mfma(const float* __restrict__ feat,
                                               const float* __restrict__ scale,
                                               const float* __restrict__ norm_w,
                                               const float* __restrict__ w_in,
                                               float* __restrict__ xr) {
    __shared__ char lds[2 * 128 * 80];
    char* As = lds;               // [128 m][40 bf16] (32 used)
    char* Bs = lds + 128 * 80;    // [128 n][40 bf16] (B^T: n-major, k contiguous)

    int t = threadIdx.x;
    int m0 = blockIdx.y * 128, n0 = blockIdx.x * 128;
    int s = m0 >> 10, p0 = m0 & 1023;

    int i = t & 127, c0 = t >> 7;          // staging: row i, chunks {c0, c0+2}
    float sc = scale[m0 + i];
    const float* fbase = feat + (size_t)s * (DMODEL * NPOS) + p0 + i;

    int l = t & 63, w = t >> 6;
    int wm = w & 1, wn = w >> 1;
    int g = l >> 4, lr = l & 15;

    f32x4 acc[4][4] = {};

    for (int k0 = 0; k0 < DMODEL; k0 += 32) {
        if (k0) __syncthreads();
        // stage A (normalized feat) and B^T (w_in)
        #pragma unroll
        for (int cc = 0; cc < 2; ++cc) {
            int c = c0 + cc * 2;
            short8 va, vb;
            #pragma unroll
            for (int j = 0; j < 8; ++j) {
                int k = k0 + c * 8 + j;
                float a = fbase[(size_t)k * NPOS] * sc * norm_w[k];
                va[j] = (short)f2bf(a);
                float b = w_in[(size_t)k * 1024 + n0 + i];
                vb[j] = (short)f2bf(b);
            }
            *reinterpret_cast<short8*>(As + i * 80 + c * 16) = va;
            *reinterpret_cast<short8*>(Bs + i * 80 + c * 16) = vb;
        }
        __syncthreads();

        short8 a[4], b[4];
        #pragma unroll
        for (int mi = 0; mi < 4; ++mi)
            a[mi] = *reinterpret_cast<short8*>(As + (wm * 64 + mi * 16 + lr) * 80 + g * 16);
        #pragma unroll
        for (int ni = 0; ni < 4; ++ni)
            b[ni] = *reinterpret_cast<short8*>(Bs + (wn * 64 + ni * 16 + lr) * 80 + g * 16);
        #pragma unroll
        for (int mi = 0; mi < 4; ++mi)
            #pragma unroll
            for (int ni = 0; ni < 4; ++ni)
                acc[mi][ni] = __builtin_amdgcn_mfma_f32_16x16x32_bf16(a[mi], b[ni], acc[mi][ni], 0, 0, 0);
    }

    #pragma unroll
    for (int mi = 0; mi < 4; ++mi) {
        #pragma unroll
        for (int r = 0; r < 4; ++r) {
            int m = m0 + wm * 64 + mi * 16 + g * 4 + r;
            #pragma unroll
            for (int ni = 0; ni < 4; ++ni) {
                int n = n0 + wn * 64 + ni * 16 + lr;
                xr[(size_t)m * 1024 + n] = acc[mi][ni][r];
            }
        }
    }
}

// ---------------- K2: depthwise causal conv (k=3) over s + SiLU ----------------
__global__ __launch_bounds__(256) void k2_conv(const float* __restrict__ xr,
                                               const float* __restrict__ conv_w,
                                               const float* __restrict__ conv_b,
                                               float* __restrict__ xm) {
    int flat = blockIdx.x * 256 + threadIdx.x;
    int d = flat & (DINNER - 1);
    int m = flat >> 9;
    int s = m >> 10;
    float w0 = conv_w[d * 3 + 0], w1 = conv_w[d * 3 + 1], w2 = conv_w[d * 3 + 2];
    float acc = conv_b[d];
    acc += xr[(size_t)m * 1024 + d] * w2;
    if (s >= 1) acc += xr[(size_t)(m - 1024) * 1024 + d] * w1;
    if (s >= 2) acc += xr[(size_t)(m - 2048) * 1024 + d] * w0;
    float sig = 1.f / (1.f + expf(-acc));
    xm[(size_t)m * DINNER + d] = acc * sig;
}

// ---------------- K3: dbc = xm @ w_xproj  (N=48) ----------------
__global__ __launch_bounds__(256) void k3_dbc(const float* __restrict__ xm,
                                              const float* __restrict__ w_xproj,
                                              float* __restrict__ dbc) {
    int flat = blockIdx.x * 256 + threadIdx.x;
    int j = flat % 48;
    int m = flat / 48;
    const float* xrow = xm + (size_t)m * DINNER;
    float acc = 0.f;
    #pragma unroll 8
    for (int k = 0; k < DINNER; ++k)
        acc += xrow[k] * w_xproj[k * 48 + j];
    dbc[(size_t)m * 48 + j] = acc;
}

// ---------------- K5: fused delta + selective scan + gates (y in-place over xm) ---
__global__ __launch_bounds__(256) void k5_scan(const float* __restrict__ xr,
                                               float* xm,  // in: xm, out: y (aliased)
                                               const float* __restrict__ dbc,
                                               const float* __restrict__ w_dt,
                                               const float* __restrict__ b_dt,
                                               const float* __restrict__ A_log,
                                               const float* __restrict__ Dp) {
    __shared__ float wdt[DTRANK][256];
    __shared__ float sdbc[48];
    int p = blockIdx.x >> 1;
    int d0 = (blockIdx.x & 1) << 8;
    int tx = threadIdx.x;
    int d = d0 + tx;
    #pragma unroll
    for (int r = 0; r < DTRANK; ++r) wdt[r][tx] = w_dt[r * DINNER + d];
    float Ar[DSTATE];
    #pragma unroll
    for (int n = 0; n < DSTATE; ++n) Ar[n] = -expf(A_log[d * DSTATE + n]);
    float Dv = Dp[d], bdt = b_dt[d];
    float h[DSTATE];
    #pragma unroll
    for (int n = 0; n < DSTATE; ++n) h[n] = 0.f;
    for (int s = 0; s < NSAMP; ++s) {
        int m = (s << 10) + p;
        __syncthreads();
        if (tx < 48) sdbc[tx] = dbc[(size_t)m * 48 + tx];
        __syncthreads();
        float dp = bdt;
        #pragma unroll
        for (int r = 0; r < DTRANK; ++r) dp += sdbc[r] * wdt[r][tx];
        float delta = (dp > 20.f) ? dp : log1pf(expf(dp));
        float u = xm[(size_t)m * DINNER + d];
        float yv = 0.f;
        #pragma unroll
        for (int n = 0; n < DSTATE; ++n) {
            float dA = expf(delta * Ar[n]);
            h[n] = dA * h[n] + delta * sdbc[16 + n] * u;
            yv += h[n] * sdbc[32 + n];
        }
        float r0 = xr[(size_t)m * 1024 + DINNER + d];
        float sig = 1.f / (1.f + expf(-r0));
        xm[(size_t)m * DINNER + d] = (yv + u * Dv) * (r0 * sig);
    }
}

// ---------------- K6: out = y @ w_out + x, bf16 MFMA, swapped operands ----------
// Computes D[c][p] = sum_k w_out[k][c] * y[m][k] so stores are p-contiguous.
// Tile: 128 c x 128 m, 4 waves (2x2), BK=32.
__global__ __launch_bounds__(256) void k6_mfma(const float* __restrict__ y,
                                               const float* __restrict__ w_out,
                                               const float* __restrict__ feat,
                                               float* __restrict__ out) {
    __shared__ char lds[2 * 128 * 80];
    char* Ws = lds;               // [128 c][40 bf16]: w_out^T, k contiguous
    char* Ys = lds + 128 * 80;    // [128 m][40 bf16]: y rows, k contiguous

    int t = threadIdx.x;
    int m0 = blockIdx.x * 128;          // m tile
    int cblk = blockIdx.y * 128;        // c tile
    int s = m0 >> 10, p0 = m0 & 1023;

    int i = t & 127, c0 = t >> 7;
    const float* ybase = y + (size_t)(m0 + i) * DINNER;

    int l = t & 63, w = t >> 6;
    int wm = w & 1, wn = w >> 1;
    int g = l >> 4, lr = l & 15;

    f32x4 acc[4][4] = {};

    for (int k0 = 0; k0 < DINNER; k0 += 32) {
        if (k0) __syncthreads();
        #pragma unroll
        for (int cc = 0; cc < 2; ++cc) {
            int c = c0 + cc * 2;
            short8 vw, vy;
            #pragma unroll
            for (int j = 0; j < 8; ++j) {
                int k = k0 + c * 8 + j;
                vw[j] = (short)f2bf(w_out[(size_t)k * DMODEL + cblk + i]);
            }
            float4 lo = *reinterpret_cast<const float4*>(ybase + k0 + c * 8);
            float4 hi = *reinterpret_cast<const float4*>(ybase + k0 + c * 8 + 4);
            vy[0] = (short)f2bf(lo.x); vy[1] = (short)f2bf(lo.y);
            vy[2] = (short)f2bf(lo.z); vy[3] = (short)f2bf(lo.w);
            vy[4] = (short)f2bf(hi.x); vy[5] = (short)f2bf(hi.y);
            vy[6] = (short)f2bf(hi.z); vy[7] = (short)f2bf(hi.w);
            *reinterpret_cast<short8*>(Ws + i * 80 + c * 16) = vw;
            *reinterpret_cast<short8*>(Ys + i * 80 + c * 16) = vy;
        }
        __syncthreads();

        short8 a[4], b[4];
        #pragma unroll
        for (int mi = 0; mi < 4; ++mi)
            a[mi] = *reinterpret_cast<short8*>(Ws + (wm * 64 + mi * 16 + lr) * 80 + g * 16);
        #pragma unroll
        for (int ni = 0; ni < 4; ++ni)
            b[ni] = *reinterpret_cast<short8*>(Ys + (wn * 64 + ni * 16 + lr) * 80 + g * 16);
        #pragma unroll
        for (int mi = 0; mi < 4; ++mi)
            #pragma unroll
            for (int ni = 0; ni < 4; ++ni)
                acc[mi][ni] = __builtin_amdgcn_mfma_f32_16x16x32_bf16(a[mi], b[ni], acc[mi][ni], 0, 0, 0);
    }

    #pragma unroll
    for (int mi = 0; mi < 4; ++mi) {
        #pragma unroll
        for (int r = 0; r < 4; ++r) {
            int c = cblk + wm * 64 + mi * 16 + g * 4 + r;
            #pragma unroll
            for (int ni = 0; ni < 4; ++ni) {
                int p = p0 + wn * 64 + ni * 16 + lr;
                size_t idx = (size_t)s * (DMODEL * NPOS) + (size_t)c * NPOS + p;
                out[idx] = acc[mi][ni][r] + feat[idx];
            }
        }
    }
}

extern "C" void kernel_launch(void* const* d_in, const int* in_sizes, int n_in,
                              void* d_out, int out_size, void* d_ws, size_t ws_size,
                              hipStream_t stream) {
    const float* feature = (const float*)d_in[0];
    const float* norm_w  = (const float*)d_in[1];
    const float* w_in    = (const float*)d_in[2];
    const float* conv_w  = (const float*)d_in[3];
    const float* conv_b  = (const float*)d_in[4];
    const float* w_xproj = (const float*)d_in[5];
    const float* w_dt    = (const float*)d_in[6];
    const float* b_dt    = (const float*)d_in[7];
    const float* A_log   = (const float*)d_in[8];
    const float* Dp      = (const float*)d_in[9];
    const float* w_out   = (const float*)d_in[10];
    float* out = (float*)d_out;

    char* ws = (char*)d_ws;
    float* scale = (float*)ws;                                   // 64 KB
    float* xr    = (float*)(ws + 65536);                         // 16384 x 1024 (64 MB)
    float* xm    = (float*)(ws + 65536 + (size_t)MROWS*1024*4);  // 16384 x 512  (32 MB), reused as y
    float* dbc   = (float*)(ws + 65536 + (size_t)MROWS*1024*4 + (size_t)MROWS*512*4); // 3 MB

    k0_scale<<<MROWS / 256, 256, 0, stream>>>(feature, scale);
    k1_mfma<<<dim3(1024 / 128, MROWS / 128), 256, 0, stream>>>(feature, scale, norm_w, w_in, xr);
    k2_conv<<<(MROWS * DINNER) / 256, 256, 0, stream>>>(xr, conv_w, conv_b, xm);
    k3_dbc<<<(MROWS * 48) / 256, 256, 0, stream>>>(xm, w_xproj, dbc);
    k5_scan<<<NPOS * 2, 256, 0, stream>>>(xr, xm, dbc, w_dt, b_dt, A_log, Dp);
    k6_mfma<<<dim3(MROWS / 128, DMODEL / 128), 256, 0, stream>>>(xm, w_out, feature, out);
}

// Round 3
// 299.663 us; speedup vs baseline: 1.8400x; 1.3326x over previous
//
#include <hip/hip_runtime.h>
#include <hip/hip_bf16.h>
#include <math.h>

// Problem dims
#define NPOS   1024
#define NSAMP  16
#define DMODEL 256
#define DINNER 512
#define DSTATE 16
#define DTRANK 16
#define MROWS  (NPOS*NSAMP)   // 16384, m = s*1024 + p
#define LOG2E  1.44269504f

typedef __attribute__((ext_vector_type(8))) short short8;
typedef __attribute__((ext_vector_type(4))) float f32x4;

// fp32 -> bf16 round-to-nearest-even (finite inputs)
__device__ __forceinline__ unsigned short f2bf(float f) {
    unsigned int u = __builtin_bit_cast(unsigned int, f);
    u = u + 0x7FFFu + ((u >> 16) & 1u);
    return (unsigned short)(u >> 16);
}
__device__ __forceinline__ float fsilu(float x) {
    return x * __builtin_amdgcn_rcpf(1.f + __expf(-x));
}

// ---------------- K0: RMS scale per row ----------------
__global__ __launch_bounds__(256) void k0_scale(const float* __restrict__ feat,
                                                float* __restrict__ scale) {
    int m = blockIdx.x * 256 + threadIdx.x;
    int s = m >> 10, p = m & 1023;
    const float* base = feat + (size_t)s * (DMODEL * NPOS) + p;
    float ss = 0.f;
    #pragma unroll 4
    for (int c = 0; c < DMODEL; ++c) {
        float v = base[(size_t)c * NPOS];
        ss += v * v;
    }
    scale[m] = rsqrtf(ss * (1.f / DMODEL) + 1e-5f);
}

// ---------------- K1: xr = rmsnorm(x) @ w_in  (M=16384,K=256,N=1024), bf16 MFMA ---
__global__ __launch_bounds__(256) void k1_mfma(const float* __restrict__ feat,
                                               const float* __restrict__ scale,
                                               const float* __restrict__ norm_w,
                                               const float* __restrict__ w_in,
                                               float* __restrict__ xr) {
    __shared__ char lds[2 * 128 * 80];
    char* As = lds;               // [128 m][40 bf16]
    char* Bs = lds + 128 * 80;    // [128 n][40 bf16] (B^T)

    int t = threadIdx.x;
    int m0 = blockIdx.y * 128, n0 = blockIdx.x * 128;
    int s = m0 >> 10, p0 = m0 & 1023;

    int i = t & 127, c0 = t >> 7;
    float sc = scale[m0 + i];
    const float* fbase = feat + (size_t)s * (DMODEL * NPOS) + p0 + i;

    int l = t & 63, w = t >> 6;
    int wm = w & 1, wn = w >> 1;
    int g = l >> 4, lr = l & 15;

    f32x4 acc[4][4] = {};

    for (int k0 = 0; k0 < DMODEL; k0 += 32) {
        if (k0) __syncthreads();
        #pragma unroll
        for (int cc = 0; cc < 2; ++cc) {
            int c = c0 + cc * 2;
            short8 va, vb;
            #pragma unroll
            for (int j = 0; j < 8; ++j) {
                int k = k0 + c * 8 + j;
                va[j] = (short)f2bf(fbase[(size_t)k * NPOS] * sc * norm_w[k]);
                vb[j] = (short)f2bf(w_in[(size_t)k * 1024 + n0 + i]);
            }
            *reinterpret_cast<short8*>(As + i * 80 + c * 16) = va;
            *reinterpret_cast<short8*>(Bs + i * 80 + c * 16) = vb;
        }
        __syncthreads();

        short8 a[4], b[4];
        #pragma unroll
        for (int mi = 0; mi < 4; ++mi)
            a[mi] = *reinterpret_cast<short8*>(As + (wm * 64 + mi * 16 + lr) * 80 + g * 16);
        #pragma unroll
        for (int ni = 0; ni < 4; ++ni)
            b[ni] = *reinterpret_cast<short8*>(Bs + (wn * 64 + ni * 16 + lr) * 80 + g * 16);
        #pragma unroll
        for (int mi = 0; mi < 4; ++mi)
            #pragma unroll
            for (int ni = 0; ni < 4; ++ni)
                acc[mi][ni] = __builtin_amdgcn_mfma_f32_16x16x32_bf16(a[mi], b[ni], acc[mi][ni], 0, 0, 0);
    }

    #pragma unroll
    for (int mi = 0; mi < 4; ++mi) {
        #pragma unroll
        for (int r = 0; r < 4; ++r) {
            int m = m0 + wm * 64 + mi * 16 + g * 4 + r;
            #pragma unroll
            for (int ni = 0; ni < 4; ++ni)
                xr[(size_t)m * 1024 + n0 + wn * 64 + ni * 16 + lr] = acc[mi][ni][r];
        }
    }
}

// ---------------- K3: dbcT[j][m] = (silu(conv(xr)) @ w_xproj)^T, bf16 MFMA --------
// A = w_xproj^T (48 rows j), B = xm rows m (conv+silu fused in staging).
// Tile: 48 j x 64 m per block, 4 waves (each 16 m), BK=32.
__global__ __launch_bounds__(256) void k3_mfma(const float* __restrict__ xr,
                                               const float* __restrict__ conv_w,
                                               const float* __restrict__ conv_b,
                                               const float* __restrict__ w_xproj,
                                               float* __restrict__ dbcT) {
    __shared__ char Ws[48 * 40];   // w_xproj^T: row j, 32 k bf16
    __shared__ char Xs[64 * 40];   // xm rows, 32 k bf16
    int t = threadIdx.x;
    int m0 = blockIdx.x * 64;
    int s = m0 >> 10;
    int l = t & 63, w = t >> 6;
    int g = l >> 4, lr = l & 15;
    int xrow = t & 63, xck = t >> 6;
    int m = m0 + xrow;

    f32x4 acc[3] = {};

    for (int k0 = 0; k0 < DINNER; k0 += 32) {
        if (k0) __syncthreads();
        #pragma unroll
        for (int q = t; q < 1536; q += 256) {
            int j = q >> 5, kk = q & 31;
            *reinterpret_cast<unsigned short*>(Ws + j * 40 + kk * 2) =
                f2bf(w_xproj[(size_t)(k0 + kk) * 48 + j]);
        }
        {
            short8 v;
            #pragma unroll
            for (int jj = 0; jj < 8; ++jj) {
                int dd = k0 + xck * 8 + jj;
                float a = conv_b[dd] + xr[(size_t)m * 1024 + dd] * conv_w[dd * 3 + 2];
                if (s >= 1) a += xr[(size_t)(m - 1024) * 1024 + dd] * conv_w[dd * 3 + 1];
                if (s >= 2) a += xr[(size_t)(m - 2048) * 1024 + dd] * conv_w[dd * 3 + 0];
                v[jj] = (short)f2bf(fsilu(a));
            }
            *reinterpret_cast<short8*>(Xs + xrow * 40 + xck * 16) = v;
        }
        __syncthreads();
        short8 b = *reinterpret_cast<short8*>(Xs + (w * 16 + lr) * 40 + g * 16);
        #pragma unroll
        for (int aj = 0; aj < 3; ++aj) {
            short8 a = *reinterpret_cast<short8*>(Ws + (aj * 16 + lr) * 40 + g * 16);
            acc[aj] = __builtin_amdgcn_mfma_f32_16x16x32_bf16(a, b, acc[aj], 0, 0, 0);
        }
    }
    #pragma unroll
    for (int aj = 0; aj < 3; ++aj)
        #pragma unroll
        for (int r = 0; r < 4; ++r)
            dbcT[(size_t)(aj * 16 + g * 4 + r) * MROWS + m0 + w * 16 + lr] = acc[aj][r];
}

// ---------------- K5: fused conv+silu + delta + scan + gates -> y (bf16) ---------
__global__ __launch_bounds__(256) void k5_scan(const float* __restrict__ xr,
                                               const float* __restrict__ dbcT,
                                               const float* __restrict__ w_dt,
                                               const float* __restrict__ b_dt,
                                               const float* __restrict__ A_log,
                                               const float* __restrict__ Dp,
                                               const float* __restrict__ conv_w,
                                               const float* __restrict__ conv_b,
                                               unsigned short* __restrict__ ybf) {
    __shared__ float sdbc[48][16];
    int p = blockIdx.x >> 1;
    int d = ((blockIdx.x & 1) << 8) + threadIdx.x;
    int tx = threadIdx.x;
    for (int q = tx; q < 768; q += 256) {
        int j = q >> 4, s = q & 15;
        sdbc[j][s] = dbcT[(size_t)j * MROWS + (s << 10) + p];
    }
    __syncthreads();

    float wdt[DTRANK], Arn[DSTATE], h[DSTATE];
    #pragma unroll
    for (int r = 0; r < DTRANK; ++r) wdt[r] = w_dt[r * DINNER + d];
    #pragma unroll
    for (int n = 0; n < DSTATE; ++n) { Arn[n] = -__expf(A_log[d * DSTATE + n]); h[n] = 0.f; }
    float w0 = conv_w[d * 3 + 0], w1 = conv_w[d * 3 + 1], w2 = conv_w[d * 3 + 2];
    float cb = conv_b[d], Dv = Dp[d], bdt = b_dt[d];
    float x1 = 0.f, x2 = 0.f;

    for (int s = 0; s < NSAMP; ++s) {
        int m = (s << 10) + p;
        float xc = xr[(size_t)m * 1024 + d];
        float r0 = xr[(size_t)m * 1024 + 512 + d];
        float cv = cb + w2 * xc + w1 * x1 + w0 * x2;
        x2 = x1; x1 = xc;
        float u = fsilu(cv);
        float dp = bdt;
        #pragma unroll
        for (int r = 0; r < DTRANK; ++r) dp += sdbc[r][s] * wdt[r];
        float delta = (dp > 20.f) ? dp : __logf(1.f + __expf(dp));
        float dl2 = delta * LOG2E, du = delta * u;
        float yv = 0.f;
        #pragma unroll
        for (int n = 0; n < DSTATE; ++n) {
            float dA = exp2f(dl2 * Arn[n]);
            h[n] = dA * h[n] + du * sdbc[16 + n][s];
            yv += h[n] * sdbc[32 + n][s];
        }
        float sg = r0 * __builtin_amdgcn_rcpf(1.f + __expf(-r0));
        ybf[(size_t)m * DINNER + d] = f2bf((yv + u * Dv) * sg);
    }
}

// ---------------- K6: out = y @ w_out + x, bf16 MFMA, swapped operands ----------
__global__ __launch_bounds__(256) void k6_mfma(const unsigned short* __restrict__ ybf,
                                               const float* __restrict__ w_out,
                                               const float* __restrict__ feat,
                                               float* __restrict__ out) {
    __shared__ char lds[2 * 128 * 80];
    char* Ws = lds;               // [128 c][40 bf16]: w_out^T
    char* Ys = lds + 128 * 80;    // [128 m][40 bf16]: y rows

    int t = threadIdx.x;
    int m0 = blockIdx.x * 128;
    int cblk = blockIdx.y * 128;
    int s = m0 >> 10, p0 = m0 & 1023;

    int i = t & 127, c0 = t >> 7;

    int l = t & 63, w = t >> 6;
    int wm = w & 1, wn = w >> 1;
    int g = l >> 4, lr = l & 15;

    f32x4 acc[4][4] = {};

    for (int k0 = 0; k0 < DINNER; k0 += 32) {
        if (k0) __syncthreads();
        #pragma unroll
        for (int cc = 0; cc < 2; ++cc) {
            int c = c0 + cc * 2;
            short8 vw;
            #pragma unroll
            for (int j = 0; j < 8; ++j) {
                int k = k0 + c * 8 + j;
                vw[j] = (short)f2bf(w_out[(size_t)k * DMODEL + cblk + i]);
            }
            *reinterpret_cast<short8*>(Ws + i * 80 + c * 16) = vw;
            short8 vy = *reinterpret_cast<const short8*>(ybf + (size_t)(m0 + i) * DINNER + k0 + c * 8);
            *reinterpret_cast<short8*>(Ys + i * 80 + c * 16) = vy;
        }
        __syncthreads();

        short8 a[4], b[4];
        #pragma unroll
        for (int mi = 0; mi < 4; ++mi)
            a[mi] = *reinterpret_cast<short8*>(Ws + (wm * 64 + mi * 16 + lr) * 80 + g * 16);
        #pragma unroll
        for (int ni = 0; ni < 4; ++ni)
            b[ni] = *reinterpret_cast<short8*>(Ys + (wn * 64 + ni * 16 + lr) * 80 + g * 16);
        #pragma unroll
        for (int mi = 0; mi < 4; ++mi)
            #pragma unroll
            for (int ni = 0; ni < 4; ++ni)
                acc[mi][ni] = __builtin_amdgcn_mfma_f32_16x16x32_bf16(a[mi], b[ni], acc[mi][ni], 0, 0, 0);
    }

    #pragma unroll
    for (int mi = 0; mi < 4; ++mi) {
        #pragma unroll
        for (int r = 0; r < 4; ++r) {
            int c = cblk + wm * 64 + mi * 16 + g * 4 + r;
            #pragma unroll
            for (int ni = 0; ni < 4; ++ni) {
                int p = p0 + wn * 64 + ni * 16 + lr;
                size_t idx = (size_t)s * (DMODEL * NPOS) + (size_t)c * NPOS + p;
                out[idx] = acc[mi][ni][r] + feat[idx];
            }
        }
    }
}

extern "C" void kernel_launch(void* const* d_in, const int* in_sizes, int n_in,
                              void* d_out, int out_size, void* d_ws, size_t ws_size,
                              hipStream_t stream) {
    const float* feature = (const float*)d_in[0];
    const float* norm_w  = (const float*)d_in[1];
    const float* w_in    = (const float*)d_in[2];
    const float* conv_w  = (const float*)d_in[3];
    const float* conv_b  = (const float*)d_in[4];
    const float* w_xproj = (const float*)d_in[5];
    const float* w_dt    = (const float*)d_in[6];
    const float* b_dt    = (const float*)d_in[7];
    const float* A_log   = (const float*)d_in[8];
    const float* Dp      = (const float*)d_in[9];
    const float* w_out   = (const float*)d_in[10];
    float* out = (float*)d_out;

    char* ws = (char*)d_ws;
    float* scale          = (float*)ws;                       // 64 KB
    float* xr             = (float*)(ws + 65536);             // 64 MB
    float* dbcT           = (float*)(ws + 67174400);          // 3 MB  (48 x 16384)
    unsigned short* ybf   = (unsigned short*)(ws + 70320128); // 16 MB (16384 x 512 bf16)

    k0_scale<<<MROWS / 256, 256, 0, stream>>>(feature, scale);
    k1_mfma<<<dim3(1024 / 128, MROWS / 128), 256, 0, stream>>>(feature, scale, norm_w, w_in, xr);
    k3_mfma<<<MROWS / 64, 256, 0, stream>>>(xr, conv_w, conv_b, w_xproj, dbcT);
    k5_scan<<<NPOS * 2, 256, 0, stream>>>(xr, dbcT, w_dt, b_dt, A_log, Dp, conv_w, conv_b, ybf);
    k6_mfma<<<dim3(MROWS / 128, DMODEL / 128), 256, 0, stream>>>(ybf, w_out, feature, out);
}

// Round 5
// 217.805 us; speedup vs baseline: 2.5315x; 1.3758x over previous
//
#include <hip/hip_runtime.h>
#include <hip/hip_bf16.h>
#include <math.h>

#define NPOS   1024
#define NSAMP  16
#define DMODEL 256
#define DINNER 512
#define DSTATE 16
#define DTRANK 16
#define MROWS  (NPOS*NSAMP)   // 16384, m = s*1024 + p
#define LOG2E  1.44269504f

typedef __attribute__((ext_vector_type(8))) short short8;
typedef __attribute__((ext_vector_type(4))) float f32x4;

__device__ __forceinline__ unsigned short f2bf(float f) {
    unsigned int u = __builtin_bit_cast(unsigned int, f);
    u = u + 0x7FFFu + ((u >> 16) & 1u);
    return (unsigned short)(u >> 16);
}
__device__ __forceinline__ float bf2f(short b) {
    unsigned int u = ((unsigned int)(unsigned short)b) << 16;
    return __builtin_bit_cast(float, u);
}
__device__ __forceinline__ float fsilu(float x) {
    return x * __builtin_amdgcn_rcpf(1.f + __expf(-x));
}

// ---------------- kprep: weight transpose+convert to bf16 ----------------
__global__ __launch_bounds__(256) void kprep(const float* __restrict__ w_in,
                                             const float* __restrict__ w_out,
                                             const float* __restrict__ w_xproj,
                                             unsigned short* __restrict__ w_inT,
                                             unsigned short* __restrict__ w_outT,
                                             unsigned short* __restrict__ wxT) {
    int idx = blockIdx.x * 256 + threadIdx.x;
    if (idx < 262144) {                       // w_inT[n][k]
        int n = idx >> 8, k = idx & 255;
        w_inT[idx] = f2bf(w_in[(size_t)k * 1024 + n]);
    } else if (idx < 262144 + 131072) {       // w_outT[c][k]
        int i = idx - 262144;
        int c = i >> 9, k = i & 511;
        w_outT[i] = f2bf(w_out[(size_t)k * DMODEL + c]);
    } else {                                  // wxT[j][k]
        int i = idx - 262144 - 131072;
        int j = i >> 9, k = i & 511;
        wxT[i] = f2bf(w_xproj[(size_t)k * 48 + j]);
    }
}

// ---------------- k0a: RMS scale per row ----------------
__global__ __launch_bounds__(256) void k0a(const float* __restrict__ feat,
                                           float* __restrict__ scale) {
    __shared__ float part[4][64];
    int t = threadIdx.x;
    int mi = t & 63, cg = t >> 6;
    int m = blockIdx.x * 64 + mi;
    int s = m >> 10, p = m & 1023;
    const float* base = feat + (size_t)s * (DMODEL * NPOS) + p;
    float ss = 0.f;
    #pragma unroll 4
    for (int c = cg * 64; c < cg * 64 + 64; ++c) {
        float v = base[(size_t)c * NPOS];
        ss += v * v;
    }
    part[cg][mi] = ss;
    __syncthreads();
    if (t < 64) {
        float tot = part[0][t] + part[1][t] + part[2][t] + part[3][t];
        scale[blockIdx.x * 64 + t] = rsqrtf(tot * (1.f / DMODEL) + 1e-5f);
    }
}

// ---------------- k0b: normalized x -> bf16, same [s][c][p] layout ----------------
__global__ __launch_bounds__(256) void k0b(const float* __restrict__ feat,
                                           const float* __restrict__ scale,
                                           const float* __restrict__ norm_w,
                                           unsigned short* __restrict__ xnbf) {
    int f = blockIdx.x * 256 + threadIdx.x;     // s*(256*1024) + c*1024 + p
    int p = f & 1023, c = (f >> 10) & 255, s = f >> 18;
    xnbf[f] = f2bf(feat[f] * scale[(s << 10) + p] * norm_w[c]);
}

// ---------------- K1: [xm|res] = rmsnorm(x) @ w_in, bf16 MFMA -------------------
// Tile 128x128, 4 waves, BK=32. n<512 -> xmbf ; n>=512 -> gbf = silu(res).
__global__ __launch_bounds__(256) void k1_mfma(const unsigned short* __restrict__ xnbf,
                                               const unsigned short* __restrict__ w_inT,
                                               unsigned short* __restrict__ xmbf,
                                               unsigned short* __restrict__ gbf) {
    __shared__ char lds[2 * 128 * 80];
    char* As = lds;
    char* Bs = lds + 128 * 80;
    int t = threadIdx.x;
    int m0 = blockIdx.y * 128, n0 = blockIdx.x * 128;
    int s = m0 >> 10, p0 = m0 & 1023;
    int i = t & 127, c0 = t >> 7;
    const unsigned short* xb = xnbf + (size_t)s * (DMODEL * NPOS) + p0 + i;
    int l = t & 63, w = t >> 6;
    int wm = w & 1, wn = w >> 1, g = l >> 4, lr = l & 15;

    f32x4 acc[4][4] = {};
    for (int k0 = 0; k0 < DMODEL; k0 += 32) {
        if (k0) __syncthreads();
        #pragma unroll
        for (int cc = 0; cc < 2; ++cc) {
            int c = c0 + cc * 2;
            short8 va;
            #pragma unroll
            for (int j = 0; j < 8; ++j)
                va[j] = (short)xb[(size_t)(k0 + c * 8 + j) * NPOS];
            *reinterpret_cast<short8*>(As + i * 80 + c * 16) = va;
            short8 vb = *reinterpret_cast<const short8*>(w_inT + (size_t)(n0 + i) * DMODEL + k0 + c * 8);
            *reinterpret_cast<short8*>(Bs + i * 80 + c * 16) = vb;
        }
        __syncthreads();
        short8 a[4], b[4];
        #pragma unroll
        for (int mi = 0; mi < 4; ++mi)
            a[mi] = *reinterpret_cast<short8*>(As + (wm * 64 + mi * 16 + lr) * 80 + g * 16);
        #pragma unroll
        for (int ni = 0; ni < 4; ++ni)
            b[ni] = *reinterpret_cast<short8*>(Bs + (wn * 64 + ni * 16 + lr) * 80 + g * 16);
        #pragma unroll
        for (int mi = 0; mi < 4; ++mi)
            #pragma unroll
            for (int ni = 0; ni < 4; ++ni)
                acc[mi][ni] = __builtin_amdgcn_mfma_f32_16x16x32_bf16(a[mi], b[ni], acc[mi][ni], 0, 0, 0);
    }
    bool isRes = (n0 >= 512);
    #pragma unroll
    for (int mi = 0; mi < 4; ++mi) {
        #pragma unroll
        for (int r = 0; r < 4; ++r) {
            int m = m0 + wm * 64 + mi * 16 + g * 4 + r;
            #pragma unroll
            for (int ni = 0; ni < 4; ++ni) {
                int n = n0 + wn * 64 + ni * 16 + lr;
                float v = acc[mi][ni][r];
                if (isRes) gbf[(size_t)m * DINNER + n - 512] = f2bf(fsilu(v));
                else       xmbf[(size_t)m * DINNER + n] = f2bf(v);
            }
        }
    }
}

// ---------------- uker: u = silu(depthwise causal conv over s) -> bf16 ----------
__global__ __launch_bounds__(256) void uker(const unsigned short* __restrict__ xmbf,
                                            const float* __restrict__ conv_w,
                                            const float* __restrict__ conv_b,
                                            unsigned short* __restrict__ ubf) {
    int f = blockIdx.x * 256 + threadIdx.x;     // one short8 (8 d) per thread
    int m = f >> 6, dd0 = (f & 63) << 3;
    int s = m >> 10;
    const unsigned short* r0 = xmbf + (size_t)m * DINNER + dd0;
    short8 x0 = *reinterpret_cast<const short8*>(r0);
    short8 x1 = {}, x2 = {};
    if (s >= 1) x1 = *reinterpret_cast<const short8*>(r0 - 1024 * DINNER);
    if (s >= 2) x2 = *reinterpret_cast<const short8*>(r0 - 2048 * DINNER);
    float wv[24], cb8[8];
    #pragma unroll
    for (int q = 0; q < 6; ++q)
        *reinterpret_cast<float4*>(&wv[q * 4]) = *reinterpret_cast<const float4*>(conv_w + dd0 * 3 + q * 4);
    *reinterpret_cast<float4*>(&cb8[0]) = *reinterpret_cast<const float4*>(conv_b + dd0);
    *reinterpret_cast<float4*>(&cb8[4]) = *reinterpret_cast<const float4*>(conv_b + dd0 + 4);
    short8 v;
    #pragma unroll
    for (int j = 0; j < 8; ++j) {
        float cv = cb8[j] + wv[3 * j + 2] * bf2f(x0[j]) + wv[3 * j + 1] * bf2f(x1[j]) + wv[3 * j] * bf2f(x2[j]);
        v[j] = (short)f2bf(fsilu(cv));
    }
    *reinterpret_cast<short8*>(ubf + (size_t)m * DINNER + dd0) = v;
}

// ---------------- K3: dbc[m][48] = u @ w_xproj, bf16 MFMA -----------------------
// A = wxT rows j (48), B = ubf rows m (64/block), BK=32, LDS stride 64B.
__global__ __launch_bounds__(256) void k3_mfma(const unsigned short* __restrict__ ubf,
                                               const unsigned short* __restrict__ wxT,
                                               float* __restrict__ dbc) {
    __shared__ char Ws[48 * 64];
    __shared__ char Xs[64 * 64];
    int t = threadIdx.x;
    int m0 = blockIdx.x * 64;
    int l = t & 63, w = t >> 6, g = l >> 4, lr = l & 15;
    int xrow = t >> 2, xck = t & 3;
    f32x4 acc[3] = {};
    for (int k0 = 0; k0 < DINNER; k0 += 32) {
        if (k0) __syncthreads();
        if (t < 192) {
            int j = t >> 2, ck = t & 3;
            *reinterpret_cast<short8*>(Ws + j * 64 + ck * 16) =
                *reinterpret_cast<const short8*>(wxT + (size_t)j * DINNER + k0 + ck * 8);
        }
        *reinterpret_cast<short8*>(Xs + xrow * 64 + xck * 16) =
            *reinterpret_cast<const short8*>(ubf + (size_t)(m0 + xrow) * DINNER + k0 + xck * 8);
        __syncthreads();
        short8 b = *reinterpret_cast<short8*>(Xs + (w * 16 + lr) * 64 + g * 16);
        #pragma unroll
        for (int aj = 0; aj < 3; ++aj) {
            short8 a = *reinterpret_cast<short8*>(Ws + (aj * 16 + lr) * 64 + g * 16);
            acc[aj] = __builtin_amdgcn_mfma_f32_16x16x32_bf16(a, b, acc[aj], 0, 0, 0);
        }
    }
    int mc = m0 + w * 16 + lr;
    #pragma unroll
    for (int aj = 0; aj < 3; ++aj)
        *reinterpret_cast<f32x4*>(dbc + (size_t)mc * 48 + aj * 16 + g * 4) = acc[aj];
}

// ---------------- K4: delta = softplus(dbc_low @ w_dt + b_dt) -> bf16 -----------
__global__ __launch_bounds__(256) void k4_delta(const float* __restrict__ dbc,
                                                const float* __restrict__ w_dt,
                                                const float* __restrict__ b_dt,
                                                unsigned short* __restrict__ dbf) {
    int m = blockIdx.x >> 1;
    int d = ((blockIdx.x & 1) << 8) + threadIdx.x;
    const float* row = dbc + (size_t)m * 48;      // block-uniform -> s_load
    float acc = b_dt[d];
    #pragma unroll
    for (int r = 0; r < 16; ++r) acc += row[r] * w_dt[r * DINNER + d];
    float delta = (acc > 20.f) ? acc : __logf(1.f + __expf(acc));
    dbf[(size_t)m * DINNER + d] = f2bf(delta);
}

// ---------------- K5: selective scan, all inputs precomputed --------------------
__global__ __launch_bounds__(256) void k5_scan(const unsigned short* __restrict__ ubf,
                                               const unsigned short* __restrict__ dbf,
                                               const unsigned short* __restrict__ gbf,
                                               const float* __restrict__ dbc,
                                               const float* __restrict__ A_log,
                                               const float* __restrict__ Dp,
                                               unsigned short* __restrict__ ybf) {
    int p = blockIdx.x >> 1;
    int d = ((blockIdx.x & 1) << 8) + threadIdx.x;
    float Ar0 = -__expf(A_log[d * DSTATE]);
    bool geo = true;
    #pragma unroll
    for (int n = 1; n < DSTATE; ++n) {
        float An = -__expf(A_log[d * DSTATE + n]);
        geo = geo && (fabsf(An - (n + 1) * Ar0) <= 1e-4f * (n + 1));
    }
    float c0 = LOG2E * Ar0;
    float Dv = Dp[d];
    float h[DSTATE];
    #pragma unroll
    for (int n = 0; n < DSTATE; ++n) h[n] = 0.f;

    size_t off = (size_t)p * DINNER + d;
    unsigned short u_pf = ubf[off], dl_pf = dbf[off], g_pf = gbf[off];

    for (int s = 0; s < NSAMP; ++s) {
        int m = (s << 10) + p;
        float u = bf2f((short)u_pf), delta = bf2f((short)dl_pf), gv = bf2f((short)g_pf);
        if (s < NSAMP - 1) {
            size_t o1 = (size_t)(m + 1024) * DINNER + d;
            u_pf = ubf[o1]; dl_pf = dbf[o1]; g_pf = gbf[o1];
        }
        const float* bc = dbc + (size_t)m * 48 + 16;   // block-uniform -> s_load
        float du = delta * u;
        float yv = 0.f;
        if (geo) {
            float r = exp2f(delta * c0);
            float rr = r;
            #pragma unroll
            for (int n = 0; n < DSTATE; ++n) {
                h[n] = rr * h[n] + du * bc[n];
                yv += h[n] * bc[16 + n];
                rr *= r;
            }
        } else {
            #pragma unroll
            for (int n = 0; n < DSTATE; ++n) {
                float An = -__expf(A_log[d * DSTATE + n]);
                float dA = __expf(delta * An);
                h[n] = dA * h[n] + du * bc[n];
                yv += h[n] * bc[16 + n];
            }
        }
        ybf[(size_t)m * DINNER + d] = f2bf((yv + u * Dv) * gv);
    }
}

// ---------------- K6: out = y @ w_out + x, bf16 MFMA, swapped operands ----------
__global__ __launch_bounds__(256) void k6_mfma(const unsigned short* __restrict__ ybf,
                                               const unsigned short* __restrict__ w_outT,
                                               const float* __restrict__ feat,
                                               float* __restrict__ out) {
    __shared__ char lds[2 * 128 * 80];
    char* Ws = lds;
    char* Ys = lds + 128 * 80;
    int t = threadIdx.x;
    int m0 = blockIdx.x * 128;
    int cblk = blockIdx.y * 128;
    int s = m0 >> 10, p0 = m0 & 1023;
    int i = t & 127, c0 = t >> 7;
    int l = t & 63, w = t >> 6;
    int wm = w & 1, wn = w >> 1, g = l >> 4, lr = l & 15;

    f32x4 acc[4][4] = {};
    for (int k0 = 0; k0 < DINNER; k0 += 32) {
        if (k0) __syncthreads();
        #pragma unroll
        for (int cc = 0; cc < 2; ++cc) {
            int c = c0 + cc * 2;
            *reinterpret_cast<short8*>(Ws + i * 80 + c * 16) =
                *reinterpret_cast<const short8*>(w_outT + (size_t)(cblk + i) * DINNER + k0 + c * 8);
            *reinterpret_cast<short8*>(Ys + i * 80 + c * 16) =
                *reinterpret_cast<const short8*>(ybf + (size_t)(m0 + i) * DINNER + k0 + c * 8);
        }
        __syncthreads();
        short8 a[4], b[4];
        #pragma unroll
        for (int mi = 0; mi < 4; ++mi)
            a[mi] = *reinterpret_cast<short8*>(Ws + (wm * 64 + mi * 16 + lr) * 80 + g * 16);
        #pragma unroll
        for (int ni = 0; ni < 4; ++ni)
            b[ni] = *reinterpret_cast<short8*>(Ys + (wn * 64 + ni * 16 + lr) * 80 + g * 16);
        #pragma unroll
        for (int mi = 0; mi < 4; ++mi)
            #pragma unroll
            for (int ni = 0; ni < 4; ++ni)
                acc[mi][ni] = __builtin_amdgcn_mfma_f32_16x16x32_bf16(a[mi], b[ni], acc[mi][ni], 0, 0, 0);
    }
    #pragma unroll
    for (int mi = 0; mi < 4; ++mi) {
        #pragma unroll
        for (int r = 0; r < 4; ++r) {
            int c = cblk + wm * 64 + mi * 16 + g * 4 + r;
            #pragma unroll
            for (int ni = 0; ni < 4; ++ni) {
                int p = p0 + wn * 64 + ni * 16 + lr;
                size_t idx = (size_t)s * (DMODEL * NPOS) + (size_t)c * NPOS + p;
                out[idx] = acc[mi][ni][r] + feat[idx];
            }
        }
    }
}

extern "C" void kernel_launch(void* const* d_in, const int* in_sizes, int n_in,
                              void* d_out, int out_size, void* d_ws, size_t ws_size,
                              hipStream_t stream) {
    const float* feature = (const float*)d_in[0];
    const float* norm_w  = (const float*)d_in[1];
    const float* w_in    = (const float*)d_in[2];
    const float* conv_w  = (const float*)d_in[3];
    const float* conv_b  = (const float*)d_in[4];
    const float* w_xproj = (const float*)d_in[5];
    const float* w_dt    = (const float*)d_in[6];
    const float* b_dt    = (const float*)d_in[7];
    const float* A_log   = (const float*)d_in[8];
    const float* Dp      = (const float*)d_in[9];
    const float* w_out   = (const float*)d_in[10];
    float* out = (float*)d_out;

    char* ws = (char*)d_ws;
    float*          scale  = (float*)(ws + 0);                  // 64 KB
    unsigned short* xmbf   = (unsigned short*)(ws + 65536);     // 16 MB
    unsigned short* gbf    = (unsigned short*)(ws + 16842752);  // 16 MB
    unsigned short* xnbf   = (unsigned short*)(ws + 33619968);  // 8.4 MB
    float*          dbc    = (float*)(ws + 42008576);           // 3 MB
    unsigned short* ubf    = (unsigned short*)(ws + 45154304);  // 16 MB
    unsigned short* dbf    = (unsigned short*)(ws + 61931520);  // 16 MB
    unsigned short* ybf    = (unsigned short*)(ws + 78708736);  // 16 MB
    unsigned short* w_inT  = (unsigned short*)(ws + 95485952);  // 512 KB
    unsigned short* w_outT = (unsigned short*)(ws + 96010240);  // 256 KB
    unsigned short* wxT    = (unsigned short*)(ws + 96272384);  // 48 KB

    kprep<<<1632, 256, 0, stream>>>(w_in, w_out, w_xproj, w_inT, w_outT, wxT);
    k0a<<<MROWS / 64, 256, 0, stream>>>(feature, scale);
    k0b<<<(MROWS * DMODEL) / 256, 256, 0, stream>>>(feature, scale, norm_w, xnbf);
    k1_mfma<<<dim3(1024 / 128, MROWS / 128), 256, 0, stream>>>(xnbf, w_inT, xmbf, gbf);
    uker<<<(MROWS * DINNER / 8) / 256, 256, 0, stream>>>(xmbf, conv_w, conv_b, ubf);
    k3_mfma<<<MROWS / 64, 256, 0, stream>>>(ubf, wxT, dbc);
    k4_delta<<<MROWS * 2, 256, 0, stream>>>(dbc, w_dt, b_dt, dbf);
    k5_scan<<<NPOS * 2, 256, 0, stream>>>(ubf, dbf, gbf, dbc, A_log, Dp, ybf);
    k6_mfma<<<dim3(MROWS / 128, DMODEL / 128), 256, 0, stream>>>(ybf, w_outT, feature, out);
}

// Round 6
// 199.822 us; speedup vs baseline: 2.7594x; 1.0900x over previous
//
#include <hip/hip_runtime.h>
#include <hip/hip_bf16.h>
#include <math.h>

#define NPOS   1024
#define NSAMP  16
#define DMODEL 256
#define DINNER 512
#define DSTATE 16
#define DTRANK 16
#define MROWS  (NPOS*NSAMP)   // 16384, m = s*1024 + p
#define LOG2E  1.44269504f

typedef __attribute__((ext_vector_type(8))) short short8;
typedef __attribute__((ext_vector_type(4))) float f32x4;

__device__ __forceinline__ unsigned short f2bf(float f) {
    unsigned int u = __builtin_bit_cast(unsigned int, f);
    u = u + 0x7FFFu + ((u >> 16) & 1u);
    return (unsigned short)(u >> 16);
}
__device__ __forceinline__ float bf2f(short b) {
    unsigned int u = ((unsigned int)(unsigned short)b) << 16;
    return __builtin_bit_cast(float, u);
}
__device__ __forceinline__ float fsilu(float x) {
    return x * __builtin_amdgcn_rcpf(1.f + __expf(-x));
}
// async global->LDS, 16B per lane, linear dest
__device__ __forceinline__ void gl16(const void* g, void* l) {
    __builtin_amdgcn_global_load_lds((const __attribute__((address_space(1))) void*)g,
                                     (__attribute__((address_space(3))) void*)l, 16, 0, 0);
}

// ---------------- kprep: weight transpose+convert to bf16 ----------------
__global__ __launch_bounds__(256) void kprep(const float* __restrict__ w_in,
                                             const float* __restrict__ w_out,
                                             const float* __restrict__ w_xproj,
                                             unsigned short* __restrict__ w_inT,
                                             unsigned short* __restrict__ w_outT,
                                             unsigned short* __restrict__ wxT) {
    int idx = blockIdx.x * 256 + threadIdx.x;
    if (idx < 262144) {                       // w_inT[n][k]
        int n = idx >> 8, k = idx & 255;
        w_inT[idx] = f2bf(w_in[(size_t)k * 1024 + n]);
    } else if (idx < 262144 + 131072) {       // w_outT[c][k]
        int i = idx - 262144;
        int c = i >> 9, k = i & 511;
        w_outT[i] = f2bf(w_out[(size_t)k * DMODEL + c]);
    } else {                                  // wxT[j][k]
        int i = idx - 262144 - 131072;
        int j = i >> 9, k = i & 511;
        wxT[i] = f2bf(w_xproj[(size_t)k * 48 + j]);
    }
}

// ---------------- knorm: RMS scale + normalize + transpose -> xnT[m][k] bf16 ----
// block = (s, 64-p tile); reads feat once, keeps values in regs.
__global__ __launch_bounds__(256) void knorm(const float* __restrict__ feat,
                                             const float* __restrict__ norm_w,
                                             unsigned short* __restrict__ xnT) {
    __shared__ float part[4][64];
    __shared__ float ssc[64];
    __shared__ char tile[64 * 520];           // [p][260 shorts] (256 used)
    int t = threadIdx.x;
    int s = blockIdx.x, p0 = blockIdx.y * 64;
    int pl = t & 63, cg = t >> 6;
    const float* base = feat + (size_t)s * (DMODEL * NPOS) + p0 + pl;
    float vals[64];
    float ss = 0.f;
    #pragma unroll
    for (int j = 0; j < 64; ++j) {
        float v = base[(size_t)(cg * 64 + j) * NPOS];
        vals[j] = v;
        ss += v * v;
    }
    part[cg][pl] = ss;
    __syncthreads();
    if (t < 64) {
        float tot = part[0][t] + part[1][t] + part[2][t] + part[3][t];
        ssc[t] = rsqrtf(tot * (1.f / DMODEL) + 1e-5f);
    }
    __syncthreads();
    float sc = ssc[pl];
    unsigned short* trow = (unsigned short*)(tile + pl * 520);
    #pragma unroll
    for (int j = 0; j < 64; ++j)
        trow[cg * 64 + j] = f2bf(vals[j] * sc * norm_w[cg * 64 + j]);
    __syncthreads();
    // write transposed: thread t -> p=t>>2, c-chunk (t&3)*64
    int p = t >> 2, cb = (t & 3) * 64;
    const unsigned short* srow = (const unsigned short*)(tile + p * 520);
    unsigned short* orow = xnT + (size_t)((s << 10) + p0 + p) * DMODEL + cb;
    #pragma unroll
    for (int j8 = 0; j8 < 8; ++j8) {
        short8 v;
        #pragma unroll
        for (int jj = 0; jj < 8; ++jj) v[jj] = srow[cb + j8 * 8 + jj];
        *reinterpret_cast<short8*>(orow + j8 * 8) = v;
    }
}

// ---------------- K1: [xm|res] = xn @ w_in, bf16 MFMA, async staging ------------
// Tile 128x128, 4 waves, BK=64, linear LDS [row][128B], global_load_lds w=16.
__global__ __launch_bounds__(256) void k1_mfma(const unsigned short* __restrict__ xnT,
                                               const unsigned short* __restrict__ w_inT,
                                               unsigned short* __restrict__ xmbf,
                                               unsigned short* __restrict__ gbf) {
    __shared__ char As[128 * 128];
    __shared__ char Bs[128 * 128];
    int t = threadIdx.x;
    int m0 = blockIdx.y * 128, n0 = blockIdx.x * 128;
    int l = t & 63, w = t >> 6;
    int wm = w & 1, wn = w >> 1, g = l >> 4, lr = l & 15;

    f32x4 acc[4][4] = {};
    for (int k0 = 0; k0 < DMODEL; k0 += 64) {
        if (k0) __syncthreads();
        #pragma unroll
        for (int q = 0; q < 4; ++q) {
            int chunk = q * 256 + t;
            int row = chunk >> 3, cb = chunk & 7;
            gl16(xnT  + (size_t)(m0 + row) * DMODEL + k0 + cb * 8, As + chunk * 16);
            gl16(w_inT + (size_t)(n0 + row) * DMODEL + k0 + cb * 8, Bs + chunk * 16);
        }
        __syncthreads();
        #pragma unroll
        for (int ks = 0; ks < 2; ++ks) {
            short8 a[4], b[4];
            #pragma unroll
            for (int mi = 0; mi < 4; ++mi)
                a[mi] = *reinterpret_cast<short8*>(As + (wm * 64 + mi * 16 + lr) * 128 + ks * 64 + g * 16);
            #pragma unroll
            for (int ni = 0; ni < 4; ++ni)
                b[ni] = *reinterpret_cast<short8*>(Bs + (wn * 64 + ni * 16 + lr) * 128 + ks * 64 + g * 16);
            #pragma unroll
            for (int mi = 0; mi < 4; ++mi)
                #pragma unroll
                for (int ni = 0; ni < 4; ++ni)
                    acc[mi][ni] = __builtin_amdgcn_mfma_f32_16x16x32_bf16(a[mi], b[ni], acc[mi][ni], 0, 0, 0);
        }
    }
    bool isRes = (n0 >= 512);
    #pragma unroll
    for (int mi = 0; mi < 4; ++mi) {
        #pragma unroll
        for (int r = 0; r < 4; ++r) {
            int m = m0 + wm * 64 + mi * 16 + g * 4 + r;
            #pragma unroll
            for (int ni = 0; ni < 4; ++ni) {
                int n = n0 + wn * 64 + ni * 16 + lr;
                float v = acc[mi][ni][r];
                if (isRes) gbf[(size_t)m * DINNER + n - 512] = f2bf(fsilu(v));
                else       xmbf[(size_t)m * DINNER + n] = f2bf(v);
            }
        }
    }
}

// ---------------- K3: dbc[m][48] = silu(conv(xm)) @ w_xproj, conv fused ---------
__global__ __launch_bounds__(256) void k3_mfma(const unsigned short* __restrict__ xmbf,
                                               const float* __restrict__ conv_w,
                                               const float* __restrict__ conv_b,
                                               const unsigned short* __restrict__ wxT,
                                               float* __restrict__ dbc) {
    __shared__ char Ws[48 * 64];
    __shared__ char Xs[64 * 64];
    int t = threadIdx.x;
    int m0 = blockIdx.x * 64;
    int s = m0 >> 10;
    int l = t & 63, w = t >> 6, g = l >> 4, lr = l & 15;
    int xrow = t >> 2, xck = t & 3;
    int m = m0 + xrow;
    f32x4 acc[3] = {};
    for (int k0 = 0; k0 < DINNER; k0 += 32) {
        if (k0) __syncthreads();
        if (t < 192) {
            int j = t >> 2, ck = t & 3;
            *reinterpret_cast<short8*>(Ws + j * 64 + ck * 16) =
                *reinterpret_cast<const short8*>(wxT + (size_t)j * DINNER + k0 + ck * 8);
        }
        {
            int d0 = k0 + xck * 8;
            const unsigned short* r0 = xmbf + (size_t)m * DINNER + d0;
            short8 x0 = *reinterpret_cast<const short8*>(r0);
            short8 x1 = {}, x2 = {};
            if (s >= 1) x1 = *reinterpret_cast<const short8*>(r0 - 1024 * DINNER);
            if (s >= 2) x2 = *reinterpret_cast<const short8*>(r0 - 2048 * DINNER);
            short8 v;
            #pragma unroll
            for (int j = 0; j < 8; ++j) {
                int dd = d0 + j;
                float cv = conv_b[dd] + conv_w[dd * 3 + 2] * bf2f(x0[j])
                         + conv_w[dd * 3 + 1] * bf2f(x1[j]) + conv_w[dd * 3 + 0] * bf2f(x2[j]);
                v[j] = (short)f2bf(fsilu(cv));
            }
            *reinterpret_cast<short8*>(Xs + xrow * 64 + xck * 16) = v;
        }
        __syncthreads();
        short8 b = *reinterpret_cast<short8*>(Xs + (w * 16 + lr) * 64 + g * 16);
        #pragma unroll
        for (int aj = 0; aj < 3; ++aj) {
            short8 a = *reinterpret_cast<short8*>(Ws + (aj * 16 + lr) * 64 + g * 16);
            acc[aj] = __builtin_amdgcn_mfma_f32_16x16x32_bf16(a, b, acc[aj], 0, 0, 0);
        }
    }
    int mc = m0 + w * 16 + lr;
    #pragma unroll
    for (int aj = 0; aj < 3; ++aj)
        *reinterpret_cast<f32x4*>(dbc + (size_t)mc * 48 + aj * 16 + g * 4) = acc[aj];
}

// ---------------- K5: conv+silu + delta + scan + gate -> ybf (all fused) --------
__global__ __launch_bounds__(256) void k5_scan(const unsigned short* __restrict__ xmbf,
                                               const unsigned short* __restrict__ gbf,
                                               const float* __restrict__ dbc,
                                               const float* __restrict__ w_dt,
                                               const float* __restrict__ b_dt,
                                               const float* __restrict__ A_log,
                                               const float* __restrict__ Dp,
                                               const float* __restrict__ conv_w,
                                               const float* __restrict__ conv_b,
                                               unsigned short* __restrict__ ybf) {
    int p = blockIdx.x >> 1;
    int d = ((blockIdx.x & 1) << 8) + threadIdx.x;
    float wdt[DTRANK];
    #pragma unroll
    for (int r = 0; r < DTRANK; ++r) wdt[r] = w_dt[r * DINNER + d];
    float Ar0 = -__expf(A_log[d * DSTATE]);
    bool geo = true;
    #pragma unroll
    for (int n = 1; n < DSTATE; ++n) {
        float An = -__expf(A_log[d * DSTATE + n]);
        geo = geo && (fabsf(An - (n + 1) * Ar0) <= 1e-4f * (n + 1));
    }
    float c0 = LOG2E * Ar0;
    float w0 = conv_w[d * 3 + 0], w1 = conv_w[d * 3 + 1], w2 = conv_w[d * 3 + 2];
    float cb = conv_b[d], Dv = Dp[d], bdt = b_dt[d];
    float h[DSTATE];
    #pragma unroll
    for (int n = 0; n < DSTATE; ++n) h[n] = 0.f;
    float x1 = 0.f, x2 = 0.f;

    for (int s = 0; s < NSAMP; ++s) {
        int m = (s << 10) + p;
        size_t off = (size_t)m * DINNER + d;
        float xc = bf2f((short)xmbf[off]);
        float gv = bf2f((short)gbf[off]);
        float cv = cb + w2 * xc + w1 * x1 + w0 * x2;
        x2 = x1; x1 = xc;
        float u = fsilu(cv);
        const float* row = dbc + (size_t)m * 48;    // block-uniform -> s_load
        float dp = bdt;
        #pragma unroll
        for (int r = 0; r < DTRANK; ++r) dp += row[r] * wdt[r];
        float delta = (dp > 20.f) ? dp : __logf(1.f + __expf(dp));
        float du = delta * u;
        float yv = 0.f;
        if (geo) {
            float rg = exp2f(delta * c0);
            float rr = rg;
            #pragma unroll
            for (int n = 0; n < DSTATE; ++n) {
                h[n] = rr * h[n] + du * row[16 + n];
                yv += h[n] * row[32 + n];
                rr *= rg;
            }
        } else {
            #pragma unroll
            for (int n = 0; n < DSTATE; ++n) {
                float An = -__expf(A_log[d * DSTATE + n]);
                float dA = __expf(delta * An);
                h[n] = dA * h[n] + du * row[16 + n];
                yv += h[n] * row[32 + n];
            }
        }
        ybf[off] = f2bf((yv + u * Dv) * gv);
    }
}

// ---------------- K6: out = y @ w_out + x, bf16 MFMA, swapped operands ----------
__global__ __launch_bounds__(256) void k6_mfma(const unsigned short* __restrict__ ybf,
                                               const unsigned short* __restrict__ w_outT,
                                               const float* __restrict__ feat,
                                               float* __restrict__ out) {
    __shared__ char lds[2 * 128 * 80];
    char* Ws = lds;
    char* Ys = lds + 128 * 80;
    int t = threadIdx.x;
    int m0 = blockIdx.x * 128;
    int cblk = blockIdx.y * 128;
    int s = m0 >> 10, p0 = m0 & 1023;
    int i = t & 127, c0 = t >> 7;
    int l = t & 63, w = t >> 6;
    int wm = w & 1, wn = w >> 1, g = l >> 4, lr = l & 15;

    f32x4 acc[4][4] = {};
    for (int k0 = 0; k0 < DINNER; k0 += 32) {
        if (k0) __syncthreads();
        #pragma unroll
        for (int cc = 0; cc < 2; ++cc) {
            int c = c0 + cc * 2;
            *reinterpret_cast<short8*>(Ws + i * 80 + c * 16) =
                *reinterpret_cast<const short8*>(w_outT + (size_t)(cblk + i) * DINNER + k0 + c * 8);
            *reinterpret_cast<short8*>(Ys + i * 80 + c * 16) =
                *reinterpret_cast<const short8*>(ybf + (size_t)(m0 + i) * DINNER + k0 + c * 8);
        }
        __syncthreads();
        short8 a[4], b[4];
        #pragma unroll
        for (int mi = 0; mi < 4; ++mi)
            a[mi] = *reinterpret_cast<short8*>(Ws + (wm * 64 + mi * 16 + lr) * 80 + g * 16);
        #pragma unroll
        for (int ni = 0; ni < 4; ++ni)
            b[ni] = *reinterpret_cast<short8*>(Ys + (wn * 64 + ni * 16 + lr) * 80 + g * 16);
        #pragma unroll
        for (int mi = 0; mi < 4; ++mi)
            #pragma unroll
            for (int ni = 0; ni < 4; ++ni)
                acc[mi][ni] = __builtin_amdgcn_mfma_f32_16x16x32_bf16(a[mi], b[ni], acc[mi][ni], 0, 0, 0);
    }
    #pragma unroll
    for (int mi = 0; mi < 4; ++mi) {
        #pragma unroll
        for (int r = 0; r < 4; ++r) {
            int c = cblk + wm * 64 + mi * 16 + g * 4 + r;
            #pragma unroll
            for (int ni = 0; ni < 4; ++ni) {
                int p = p0 + wn * 64 + ni * 16 + lr;
                size_t idx = (size_t)s * (DMODEL * NPOS) + (size_t)c * NPOS + p;
                out[idx] = acc[mi][ni][r] + feat[idx];
            }
        }
    }
}

extern "C" void kernel_launch(void* const* d_in, const int* in_sizes, int n_in,
                              void* d_out, int out_size, void* d_ws, size_t ws_size,
                              hipStream_t stream) {
    const float* feature = (const float*)d_in[0];
    const float* norm_w  = (const float*)d_in[1];
    const float* w_in    = (const float*)d_in[2];
    const float* conv_w  = (const float*)d_in[3];
    const float* conv_b  = (const float*)d_in[4];
    const float* w_xproj = (const float*)d_in[5];
    const float* w_dt    = (const float*)d_in[6];
    const float* b_dt    = (const float*)d_in[7];
    const float* A_log   = (const float*)d_in[8];
    const float* Dp      = (const float*)d_in[9];
    const float* w_out   = (const float*)d_in[10];
    float* out = (float*)d_out;

    char* ws = (char*)d_ws;
    unsigned short* xnT    = (unsigned short*)(ws + 0);         // 8.4 MB
    unsigned short* xmbf   = (unsigned short*)(ws + 8388608);   // 16.8 MB
    unsigned short* gbf    = (unsigned short*)(ws + 25165824);  // 16.8 MB
    float*          dbc    = (float*)(ws + 41943040);           // 3.1 MB
    unsigned short* ybf    = (unsigned short*)(ws + 45088768);  // 16.8 MB
    unsigned short* w_inT  = (unsigned short*)(ws + 61865984);  // 512 KB
    unsigned short* w_outT = (unsigned short*)(ws + 62390272);  // 256 KB
    unsigned short* wxT    = (unsigned short*)(ws + 62652416);  // 48 KB

    kprep<<<1632, 256, 0, stream>>>(w_in, w_out, w_xproj, w_inT, w_outT, wxT);
    knorm<<<dim3(NSAMP, NPOS / 64), 256, 0, stream>>>(feature, norm_w, xnT);
    k1_mfma<<<dim3(1024 / 128, MROWS / 128), 256, 0, stream>>>(xnT, w_inT, xmbf, gbf);
    k3_mfma<<<MROWS / 64, 256, 0, stream>>>(xmbf, conv_w, conv_b, wxT, dbc);
    k5_scan<<<NPOS * 2, 256, 0, stream>>>(xmbf, gbf, dbc, w_dt, b_dt, A_log, Dp, conv_w, conv_b, ybf);
    k6_mfma<<<dim3(MROWS / 128, DMODEL / 128), 256, 0, stream>>>(ybf, w_outT, feature, out);
}